// Round 1
// baseline (157.286 us; speedup 1.0000x reference)
//
#include <hip/hip_runtime.h>

// Problem constants (match reference file)
#define NROWS   256
#define DCOLS   65536
#define MAXLEN  8192
#define TPB     1024
#define EPT     (DCOLS / TPB)   // 64 elements per thread
#define V4PT    (EPT / 4)       // 16 float4 per thread

// y[i,j] = x[i,j] if x[i,j]!=0 and rank_of_j_among_nonzeros(row i) < MAXLEN, else 0.
__global__ __launch_bounds__(TPB) void condense_roundtrip_kernel(
        const float* __restrict__ x, float* __restrict__ y) {
    const int row  = blockIdx.x;
    const int t    = threadIdx.x;
    const int lane = t & 63;
    const int wave = t >> 6;

    const float4* __restrict__ x4 =
        reinterpret_cast<const float4*>(x + (size_t)row * DCOLS) + t * V4PT;
    float4* __restrict__ y4 =
        reinterpret_cast<float4*>(y + (size_t)row * DCOLS) + t * V4PT;

    // ---- Pass 1: count nonzeros in this thread's contiguous chunk ----
    int cnt = 0;
#pragma unroll
    for (int i = 0; i < V4PT; ++i) {
        float4 v = x4[i];
        cnt += (v.x != 0.0f) + (v.y != 0.0f) + (v.z != 0.0f) + (v.w != 0.0f);
    }

    // ---- Block-wide exclusive scan of cnt (chunk order == element order) ----
    // Wave-level inclusive scan (wave = 64 lanes on CDNA).
    int incl = cnt;
#pragma unroll
    for (int off = 1; off < 64; off <<= 1) {
        int n = __shfl_up(incl, off, 64);
        if (lane >= off) incl += n;
    }

    __shared__ int wsum[TPB / 64];   // per-wave totals (16)
    __shared__ int wbase[TPB / 64];  // exclusive prefix of wave totals
    if (lane == 63) wsum[wave] = incl;
    __syncthreads();
    if (t == 0) {
        int acc = 0;
#pragma unroll
        for (int w = 0; w < TPB / 64; ++w) { wbase[w] = acc; acc += wsum[w]; }
    }
    __syncthreads();

    // Exclusive rank of the first element of this thread's chunk.
    int rank = wbase[wave] + (incl - cnt);

    // ---- Pass 2: re-read chunk (L2-hot) and write x or 0 with rank cutoff ----
#pragma unroll
    for (int i = 0; i < V4PT; ++i) {
        float4 v = x4[i];
        float4 o;
        bool nx = (v.x != 0.0f); o.x = (nx && rank < MAXLEN) ? v.x : 0.0f; rank += nx;
        bool ny = (v.y != 0.0f); o.y = (ny && rank < MAXLEN) ? v.y : 0.0f; rank += ny;
        bool nz = (v.z != 0.0f); o.z = (nz && rank < MAXLEN) ? v.z : 0.0f; rank += nz;
        bool nw = (v.w != 0.0f); o.w = (nw && rank < MAXLEN) ? v.w : 0.0f; rank += nw;
        y4[i] = o;
    }
}

extern "C" void kernel_launch(void* const* d_in, const int* in_sizes, int n_in,
                              void* d_out, int out_size, void* d_ws, size_t ws_size,
                              hipStream_t stream) {
    // d_in[0] = t (1 float, unused), d_in[1] = x (256*65536 f32),
    // d_in[2] = embed_table (unused by the output).
    const float* x = (const float*)d_in[1];
    float* y = (float*)d_out;
    condense_roundtrip_kernel<<<NROWS, TPB, 0, stream>>>(x, y);
}

// Round 2
// 137.355 us; speedup vs baseline: 1.1451x; 1.1451x over previous
//
#include <hip/hip_runtime.h>

// Problem constants (match reference file)
#define NROWS   256
#define DCOLS   65536
#define MAXLEN  8192
#define TPB     1024
#define V4PT    16              // float4 per thread (16*4*1024 = 65536)
#define NWAVE   (TPB / 64)

// Semantics: y[i,j] = x[i,j] if x[i,j]!=0 and rank of j among row i's
// nonzeros < MAXLEN, else 0.  When row_nnz <= MAXLEN this is exactly y = x.
__global__ __launch_bounds__(TPB) void condense_roundtrip_kernel(
        const float* __restrict__ x, float* __restrict__ y) {
    const int row  = blockIdx.x;
    const int t    = threadIdx.x;
    const int lane = t & 63;
    const int wave = t >> 6;

    const float4* __restrict__ x4 =
        reinterpret_cast<const float4*>(x + (size_t)row * DCOLS);
    float4* __restrict__ y4 =
        reinterpret_cast<float4*>(y + (size_t)row * DCOLS);

    // ---- Coalesced read: iter i, thread t -> element i*TPB + t.
    //      Each wave instruction covers one contiguous 1 KB segment. ----
    float4 v[V4PT];
    int cnt = 0;
#pragma unroll
    for (int i = 0; i < V4PT; ++i) {
        v[i] = x4[i * TPB + t];
        cnt += (v[i].x != 0.0f) + (v[i].y != 0.0f) +
               (v[i].z != 0.0f) + (v[i].w != 0.0f);
    }

    // ---- Row nnz: wave butterfly reduce + tiny LDS reduce ----
    int s = cnt;
#pragma unroll
    for (int off = 32; off; off >>= 1) s += __shfl_xor(s, off, 64);

    __shared__ int wsum[NWAVE];
    __shared__ int wbase[NWAVE];   // slow path only
    __shared__ int nnz_sh;
    if (lane == 0) wsum[wave] = s;
    __syncthreads();
    if (t == 0) {
        int acc = 0;
#pragma unroll
        for (int w = 0; w < NWAVE; ++w) acc += wsum[w];
        nnz_sh = acc;
    }
    __syncthreads();
    const int nnz = nnz_sh;   // block-uniform

    if (nnz <= MAXLEN) {
        // Every nonzero survives the truncation -> y == x. Write back registers.
#pragma unroll
        for (int i = 0; i < V4PT; ++i) y4[i * TPB + t] = v[i];
        return;
    }

    // ---- Slow path (row_nnz > MAXLEN; not taken for this data, kept for
    //      correctness). Ordered rank cutoff over contiguous per-thread
    //      chunks; re-reads are L2/L3-hot. ----
    const float4* __restrict__ xc = x4 + t * V4PT;
    float4* __restrict__ yc = y4 + t * V4PT;

    int ccnt = 0;
#pragma unroll
    for (int i = 0; i < V4PT; ++i) {
        float4 w = xc[i];
        ccnt += (w.x != 0.0f) + (w.y != 0.0f) + (w.z != 0.0f) + (w.w != 0.0f);
    }
    // wave inclusive scan
    int incl = ccnt;
#pragma unroll
    for (int off = 1; off < 64; off <<= 1) {
        int n = __shfl_up(incl, off, 64);
        if (lane >= off) incl += n;
    }
    if (lane == 63) wsum[wave] = incl;
    __syncthreads();
    if (t == 0) {
        int acc = 0;
#pragma unroll
        for (int w = 0; w < NWAVE; ++w) { wbase[w] = acc; acc += wsum[w]; }
    }
    __syncthreads();
    int rank = wbase[wave] + (incl - ccnt);   // exclusive rank at chunk start

#pragma unroll
    for (int i = 0; i < V4PT; ++i) {
        float4 w = xc[i];
        float4 o;
        bool nx = (w.x != 0.0f); o.x = (nx && rank < MAXLEN) ? w.x : 0.0f; rank += nx;
        bool ny = (w.y != 0.0f); o.y = (ny && rank < MAXLEN) ? w.y : 0.0f; rank += ny;
        bool nz = (w.z != 0.0f); o.z = (nz && rank < MAXLEN) ? w.z : 0.0f; rank += nz;
        bool nw = (w.w != 0.0f); o.w = (nw && rank < MAXLEN) ? w.w : 0.0f; rank += nw;
        yc[i] = o;
    }
}

extern "C" void kernel_launch(void* const* d_in, const int* in_sizes, int n_in,
                              void* d_out, int out_size, void* d_ws, size_t ws_size,
                              hipStream_t stream) {
    // d_in[0] = t (unused), d_in[1] = x (256*65536 f32), d_in[2] = embed_table (unused).
    const float* x = (const float*)d_in[1];
    float* y = (float*)d_out;
    condense_roundtrip_kernel<<<NROWS, TPB, 0, stream>>>(x, y);
}